// Round 3
// baseline (399.553 us; speedup 1.0000x reference)
//
#include <hip/hip_runtime.h>
#include <cstdint>
#include <math.h>

#define BB 256
#define CC 64
#define TT 4000
#define NHID 64
#define NOUT 64
#define NMLP (NOUT*(CC+1))  // 4160

// ---------------- K1: fused per-channel log-variance + MLP hypernetwork ----------------
// grid 256 (one block per sample b), block 1024. 16 threads per channel row.
// Produces wsB[b][o] and transposed wsW[b][c][o].
__global__ __launch_bounds__(1024) void k_feat(const float* __restrict__ x,
                                               const float* __restrict__ W1,
                                               const float* __restrict__ b1,
                                               const float* __restrict__ W2,
                                               const float* __restrict__ b2,
                                               float* __restrict__ wsW,
                                               float* __restrict__ wsB) {
    int b   = blockIdx.x;
    int tid = threadIdx.x;
    int c   = tid >> 4;      // 0..63
    int sub = tid & 15;      // 0..15

    const float4* row = (const float4*)(x + (size_t)b * (CC * TT) + (size_t)c * TT);
    float s = 0.f, ss = 0.f;
    #pragma unroll 4
    for (int i = sub; i < TT / 4; i += 16) {   // 1000 float4 per row / 16 threads
        float4 v = row[i];
        s  += v.x + v.y + v.z + v.w;
        ss += v.x * v.x + v.y * v.y + v.z * v.z + v.w * v.w;
    }
    // reduce within each 16-lane group (off 8,4,2,1 stay inside the group)
    #pragma unroll
    for (int off = 8; off > 0; off >>= 1) {
        s  += __shfl_xor(s, off);
        ss += __shfl_xor(ss, off);
    }

    __shared__ float fs[CC];
    __shared__ float hs[NHID];
    if (sub == 0) {
        float var = (ss - s * s / (float)TT) / (float)(TT - 1);
        float f = logf(var);
        if (isinf(f) && f < 0.f) f = 0.f;   // jnp.where(isneginf, 0, .)
        fs[c] = f;
    }
    __syncthreads();

    if (tid < NHID) {
        float v = b1[tid];
        #pragma unroll 8
        for (int k = 0; k < CC; ++k) v = fmaf(fs[k], W1[k * NHID + tid], v);
        hs[tid] = v > 0.f ? v : 0.f;
    }
    __syncthreads();

    for (int j = tid; j < NMLP; j += 1024) {
        float v = b2[j];
        #pragma unroll 8
        for (int k = 0; k < NHID; ++k) v = fmaf(hs[k], W2[k * NMLP + j], v);
        if (j < NOUT) {
            wsB[b * NOUT + j] = v;
        } else {
            int kk = j - NOUT;
            int o = kk >> 6, c2 = kk & 63;           // mlp_out[64 + o*64 + c] = W[o][c]
            wsW[(size_t)b * 4096 + c2 * 64 + o] = v; // store transposed [c][o]
        }
    }
}

// ---------------- K2: out[b,o,t] = sum_c W[o,c]*x[b,c,t] + bias[o] ----------------
// grid (8, 256), block 256. Two t per thread (float2), W/bias via uniform
// (scalarized) loads, 8-deep register prefetch of x to hide HBM latency.
__global__ __launch_bounds__(256, 2) void k_apply(const float* __restrict__ x,
                                                  const float* __restrict__ wsW,
                                                  const float* __restrict__ wsB,
                                                  float* __restrict__ out) {
    int b   = blockIdx.y;
    int tid = threadIdx.x;
    int tp  = blockIdx.x * 256 + tid;        // t-pair index, 0..2047
    bool valid = tp < TT / 2;                // 2000 pairs
    int tpc = valid ? tp : (TT / 2 - 1);

    const float*  wb = wsW + (size_t)b * 4096;   // uniform -> s_load
    const float*  bb = wsB + (size_t)b * 64;     // uniform -> s_load
    const float2* xb = (const float2*)(x + (size_t)b * (CC * TT));  // row stride 2000

    float2 acc[64];
    #pragma unroll
    for (int o = 0; o < 64; ++o) {
        float bv = bb[o];
        acc[o].x = bv; acc[o].y = bv;
    }

    float2 xv[64];                            // only ~8 live at a time
    #pragma unroll
    for (int c = 0; c < 8; ++c) xv[c] = xb[(size_t)c * (TT / 2) + tpc];

    #pragma unroll
    for (int c = 0; c < 64; ++c) {
        if (c < 56) xv[c + 8] = xb[(size_t)(c + 8) * (TT / 2) + tpc];  // prefetch
        float2 xvc = xv[c];
        const float* wrow = wb + c * 64;      // uniform row -> SGPRs
        #pragma unroll
        for (int o = 0; o < 64; ++o) {
            float w = wrow[o];
            acc[o].x = fmaf(w, xvc.x, acc[o].x);
            acc[o].y = fmaf(w, xvc.y, acc[o].y);
        }
    }

    if (!valid) return;
    float2* ob = (float2*)(out + (size_t)b * (NOUT * TT)) + tp;
    #pragma unroll
    for (int o = 0; o < 64; ++o) ob[(size_t)o * (TT / 2)] = acc[o];
}

extern "C" void kernel_launch(void* const* d_in, const int* in_sizes, int n_in,
                              void* d_out, int out_size, void* d_ws, size_t ws_size,
                              hipStream_t stream) {
    const float* x  = (const float*)d_in[0];
    const float* W1 = (const float*)d_in[1];
    const float* b1 = (const float*)d_in[2];
    const float* W2 = (const float*)d_in[3];
    const float* b2 = (const float*)d_in[4];
    float* out = (float*)d_out;
    float* ws  = (float*)d_ws;

    float* wsB = ws;              // 256*64   = 16384 floats
    float* wsW = ws + 16384;      // 256*4096 = 1048576 floats

    k_feat<<<256, 1024, 0, stream>>>(x, W1, b1, W2, b2, wsW, wsB);
    k_apply<<<dim3(8, 256), 256, 0, stream>>>(x, wsW, wsB, out);
}

// Round 4
// 368.560 us; speedup vs baseline: 1.0841x; 1.0841x over previous
//
#include <hip/hip_runtime.h>
#include <cstdint>
#include <math.h>

#define BB 256
#define CC 64
#define TT 4000
#define NHID 64
#define NOUT 64
#define NMLP (NOUT*(CC+1))  // 4160
#define TCH 128             // t per k_apply block

// ---------------- K1: fused per-channel log-variance + MLP hypernetwork ----------------
// grid 256 (one block per sample b), block 1024. 16 threads per channel row.
// Produces wsB[b][o] and transposed wsW[b][c][o].
__global__ __launch_bounds__(1024) void k_feat(const float* __restrict__ x,
                                               const float* __restrict__ W1,
                                               const float* __restrict__ b1,
                                               const float* __restrict__ W2,
                                               const float* __restrict__ b2,
                                               float* __restrict__ wsW,
                                               float* __restrict__ wsB) {
    int b   = blockIdx.x;
    int tid = threadIdx.x;
    int c   = tid >> 4;      // 0..63
    int sub = tid & 15;      // 0..15

    const float4* row = (const float4*)(x + (size_t)b * (CC * TT) + (size_t)c * TT);
    float s = 0.f, ss = 0.f;
    #pragma unroll 4
    for (int i = sub; i < TT / 4; i += 16) {   // 1000 float4 per row / 16 threads
        float4 v = row[i];
        s  += v.x + v.y + v.z + v.w;
        ss += v.x * v.x + v.y * v.y + v.z * v.z + v.w * v.w;
    }
    #pragma unroll
    for (int off = 8; off > 0; off >>= 1) {
        s  += __shfl_xor(s, off);
        ss += __shfl_xor(ss, off);
    }

    __shared__ float fs[CC];
    __shared__ float hs[NHID];
    if (sub == 0) {
        float var = (ss - s * s / (float)TT) / (float)(TT - 1);
        float f = logf(var);
        if (isinf(f) && f < 0.f) f = 0.f;   // jnp.where(isneginf, 0, .)
        fs[c] = f;
    }
    __syncthreads();

    if (tid < NHID) {
        float v = b1[tid];
        #pragma unroll 8
        for (int k = 0; k < CC; ++k) v = fmaf(fs[k], W1[k * NHID + tid], v);
        hs[tid] = v > 0.f ? v : 0.f;
    }
    __syncthreads();

    for (int j = tid; j < NMLP; j += 1024) {
        float v = b2[j];
        #pragma unroll 8
        for (int k = 0; k < NHID; ++k) v = fmaf(hs[k], W2[k * NMLP + j], v);
        if (j < NOUT) {
            wsB[b * NOUT + j] = v;
        } else {
            int kk = j - NOUT;
            int o = kk >> 6, c2 = kk & 63;           // mlp_out[64 + o*64 + c] = W[o][c]
            wsW[(size_t)b * 4096 + c2 * 64 + o] = v; // store transposed [c][o]
        }
    }
}

// ---------------- K2: out[b,o,t] = sum_c W[o,c]*x[b,c,t] + bias[o] ----------------
// grid (32, 256), block 256 (4 waves). x tile [64 c][128 t] staged in LDS (32 KB,
// 5 blocks/CU). Wave w computes o in [16w,16w+16): float2 acc[16] (32 VGPR, no
// spill possible). Per c: 1 conflict-free ds_read_b64 + 32 v_fmac with SGPR w.
// b reversed so this pass consumes the tail of x k_feat left in L3.
__global__ __launch_bounds__(256) void k_apply(const float* __restrict__ x,
                                               const float* __restrict__ wsW,
                                               const float* __restrict__ wsB,
                                               float* __restrict__ out) {
    int b    = (BB - 1) - blockIdx.y;
    int tb   = blockIdx.x * TCH;
    int tid  = threadIdx.x;
    int wave = tid >> 6, lane = tid & 63;
    int nv   = (TT - tb) < TCH ? (TT - tb) : TCH;   // valid t in chunk (32 or 128)

    __shared__ float xs[CC][TCH];

    // ---- stage x[b][:, tb..tb+nv) : 2048 float4, 8 per thread ----
    const float* xb = x + (size_t)b * (CC * TT) + tb;
    #pragma unroll
    for (int r = 0; r < 8; ++r) {
        int idx = r * 256 + tid;
        int c   = idx >> 5;                 // 32 float4 per row
        int pos = (idx & 31) * 4;
        int posc = pos < nv ? pos : (nv - 4);
        float4 v = *(const float4*)(xb + (size_t)c * TT + posc);
        *(float4*)&xs[c][pos] = v;
    }
    __syncthreads();

    const float* wb = wsW + (size_t)b * 4096;   // uniform -> s_load, [c][o]
    const float* bb = wsB + (size_t)b * 64;     // uniform -> s_load
    int ob0 = wave * 16;

    float2 acc[16];
    #pragma unroll
    for (int o = 0; o < 16; ++o) {
        float bv = bb[ob0 + o];
        acc[o].x = bv; acc[o].y = bv;
    }

    #pragma unroll
    for (int c = 0; c < CC; ++c) {
        float2 xv = *(const float2*)&xs[c][lane * 2];
        const float* wrow = wb + c * 64 + ob0;  // uniform row -> SGPRs
        #pragma unroll
        for (int o = 0; o < 16; ++o) {
            float w = wrow[o];
            acc[o].x = fmaf(w, xv.x, acc[o].x);
            acc[o].y = fmaf(w, xv.y, acc[o].y);
        }
    }

    int t0 = lane * 2;
    if (t0 < nv) {
        float* op = out + (size_t)b * (NOUT * TT) + tb + t0;
        #pragma unroll
        for (int o = 0; o < 16; ++o)
            *(float2*)(op + (size_t)(ob0 + o) * TT) = acc[o];
    }
}

extern "C" void kernel_launch(void* const* d_in, const int* in_sizes, int n_in,
                              void* d_out, int out_size, void* d_ws, size_t ws_size,
                              hipStream_t stream) {
    const float* x  = (const float*)d_in[0];
    const float* W1 = (const float*)d_in[1];
    const float* b1 = (const float*)d_in[2];
    const float* W2 = (const float*)d_in[3];
    const float* b2 = (const float*)d_in[4];
    float* out = (float*)d_out;
    float* ws  = (float*)d_ws;

    float* wsB = ws;              // 256*64   = 16384 floats
    float* wsW = ws + 16384;      // 256*4096 = 1048576 floats

    k_feat<<<256, 1024, 0, stream>>>(x, W1, b1, W2, b2, wsW, wsB);
    k_apply<<<dim3(32, 256), 256, 0, stream>>>(x, wsW, wsB, out);
}